// Round 8
// baseline (355.938 us; speedup 1.0000x reference)
//
#include <hip/hip_runtime.h>
#include <hip/hip_cooperative_groups.h>
#include <hip/hip_bf16.h>

namespace cg = cooperative_groups;

// Problem constants
#define BB 96    // batch
#define HH 100   // history length
#define NN 128   // candidates (broadcast only)
#define DD 768   // embed dim
#define AA 256   // attention dim

static __device__ __forceinline__ float dot4(float4 a, float4 b) {
  return a.x * b.x + a.y * b.y + a.z * b.z + a.w * b.w;
}

// ===========================================================================
// Phase bodies — shared between the cooperative mega-kernel and the fallback
// per-phase kernels. Each takes a flat unit index u; all intra-block syncs are
// in block-uniform control flow (u is blockIdx-derived).
// ===========================================================================

// P0: u in [0,864): 576 WrT tiles, 192 WKT tiles, 96 neigh means
static __device__ void phase_prep(int u, int tid,
                                  const float* __restrict__ Wr, const float* __restrict__ WK,
                                  const float* __restrict__ hist,
                                  float* __restrict__ WrT, float* __restrict__ WKT,
                                  float* __restrict__ neigh, float (*tile)[33]) {
  if (u < 768) {
    const float* src; float* dst; int R, C, bx, by;
    if (u < 576) { src = Wr; dst = WrT; R = DD; C = DD; bx = u % 24; by = u / 24; }
    else { int id = u - 576; src = WK; dst = WKT; R = AA; C = DD; bx = id % 24; by = id / 24; }
    int tx = tid & 31, ty = tid >> 5;
    int c0 = bx * 32, r0 = by * 32;
#pragma unroll
    for (int k = 0; k < 4; ++k)
      tile[ty + 8 * k][tx] = src[(size_t)(r0 + ty + 8 * k) * C + c0 + tx];
    __syncthreads();
#pragma unroll
    for (int k = 0; k < 4; ++k)
      dst[(size_t)(c0 + ty + 8 * k) * R + r0 + tx] = tile[tx][ty + 8 * k];
    __syncthreads();  // tile reusable next grid-stride iteration
  } else {
    int b = u - 768;
    if (tid < 192) {  // 192 float4 = 768 floats
      const float* hb = hist + (size_t)b * HH * DD + tid * 4;
      float4 a0 = make_float4(0.f, 0.f, 0.f, 0.f);
      float4 a1 = make_float4(0.f, 0.f, 0.f, 0.f);
#pragma unroll 8
      for (int h = 0; h < 96; h += 2) {
        float4 x = *(const float4*)(hb + (size_t)h * DD);
        float4 y = *(const float4*)(hb + (size_t)(h + 1) * DD);
        a0.x += x.x; a0.y += x.y; a0.z += x.z; a0.w += x.w;
        a1.x += y.x; a1.y += y.y; a1.z += y.z; a1.w += y.w;
      }
      float4 m = make_float4((a0.x + a1.x) * (1.f / 96.f), (a0.y + a1.y) * (1.f / 96.f),
                             (a0.z + a1.z) * (1.f / 96.f), (a0.w + a1.w) * (1.f / 96.f));
      *(float4*)(neigh + (size_t)b * DD + tid * 4) = m;
    }
    __syncthreads();
  }
}

// P1: u in [0,768): nl[b,e], u0[b,e]; e0=(u%24)*32, b0=(u/24)*3
static __device__ void phase_nlu0(int u, int tid,
                                  const float* __restrict__ neigh, const float* __restrict__ hist,
                                  const float* __restrict__ Wl, const float* __restrict__ bl,
                                  const float* __restrict__ Wr,
                                  float* __restrict__ nl, float* __restrict__ u0) {
  int e0 = (u % 24) * 32;
  int b0 = (u / 24) * 3;
  int lane = tid & 63, wave = tid >> 6;
  float4 xn[3][3], xh[3][3];
#pragma unroll
  for (int bi = 0; bi < 3; ++bi) {
    int b = b0 + bi;
#pragma unroll
    for (int jj = 0; jj < 3; ++jj) {
      int idx = lane + 64 * jj;
      xn[bi][jj] = ((const float4*)(neigh + (size_t)b * DD))[idx];
      xh[bi][jj] = ((const float4*)(hist + (size_t)b * HH * DD))[idx];  // h=0 row
    }
  }
  for (int i = 0; i < 8; ++i) {
    int e = e0 + wave * 8 + i;
    const float4* wl4 = (const float4*)(Wl + (size_t)e * DD);
    const float4* wr4 = (const float4*)(Wr + (size_t)e * DD);
    float pl[3] = {0.f, 0.f, 0.f}, pr[3] = {0.f, 0.f, 0.f};
#pragma unroll
    for (int jj = 0; jj < 3; ++jj) {
      float4 wl = wl4[lane + 64 * jj];
      float4 wr = wr4[lane + 64 * jj];
#pragma unroll
      for (int bi = 0; bi < 3; ++bi) {
        pl[bi] += dot4(wl, xn[bi][jj]);
        pr[bi] += dot4(wr, xh[bi][jj]);
      }
    }
#pragma unroll
    for (int bi = 0; bi < 3; ++bi) {
      float pp = pl[bi], qq = pr[bi];
      for (int off = 32; off; off >>= 1) {
        pp += __shfl_down(pp, off, 64);
        qq += __shfl_down(qq, off, 64);
      }
      if (lane == 0) {
        float nle = pp + bl[e];
        nl[(size_t)(b0 + bi) * DD + e] = nle;
        u0[(size_t)(b0 + bi) * DD + e] = qq + nle;
      }
    }
  }
}

// P2: u in [0,256): Q[b,a]; a0=(u%8)*32, b0=(u/8)*3
static __device__ void phase_q(int u, int tid,
                               const float* __restrict__ u0, const float* __restrict__ WQ,
                               const float* __restrict__ bQ, float* __restrict__ Qm) {
  int a0 = (u % 8) * 32;
  int b0 = (u / 8) * 3;
  int lane = tid & 63, wave = tid >> 6;
  float4 x[3][3];
#pragma unroll
  for (int bi = 0; bi < 3; ++bi)
#pragma unroll
    for (int jj = 0; jj < 3; ++jj)
      x[bi][jj] = ((const float4*)(u0 + (size_t)(b0 + bi) * DD))[lane + 64 * jj];
  for (int i = 0; i < 8; ++i) {
    int a = a0 + wave * 8 + i;
    const float4* w4 = (const float4*)(WQ + (size_t)a * DD);
    float p[3] = {0.f, 0.f, 0.f};
#pragma unroll
    for (int jj = 0; jj < 3; ++jj) {
      float4 w = w4[lane + 64 * jj];
#pragma unroll
      for (int bi = 0; bi < 3; ++bi) p[bi] += dot4(w, x[bi][jj]);
    }
#pragma unroll
    for (int bi = 0; bi < 3; ++bi) {
      float pp = p[bi];
      for (int off = 32; off; off >>= 1) pp += __shfl_down(pp, off, 64);
      if (lane == 0) Qm[(size_t)(b0 + bi) * AA + a] = pp + bQ[a];
    }
  }
}

// P3: u in [0,768): qk[b,d] = Q[b,:]·WKT[d,:]; d0=(u%24)*32, b0=(u/24)*3
static __device__ void phase_qk(int u, int tid,
                                const float* __restrict__ Qm, const float* __restrict__ WKT,
                                float* __restrict__ qk) {
  int d0 = (u % 24) * 32;
  int b0 = (u / 24) * 3;
  int lane = tid & 63, wave = tid >> 6;
  float4 x[3];
#pragma unroll
  for (int bi = 0; bi < 3; ++bi)
    x[bi] = ((const float4*)(Qm + (size_t)(b0 + bi) * AA))[lane];
  for (int i = 0; i < 8; ++i) {
    int d = d0 + wave * 8 + i;
    float4 w = ((const float4*)(WKT + (size_t)d * AA))[lane];
    float p[3];
#pragma unroll
    for (int bi = 0; bi < 3; ++bi) p[bi] = dot4(w, x[bi]);
#pragma unroll
    for (int bi = 0; bi < 3; ++bi) {
      float pp = p[bi];
      for (int off = 32; off; off >>= 1) pp += __shfl_down(pp, off, 64);
      if (lane == 0) qk[(size_t)(b0 + bi) * DD + d] = pp;
    }
  }
}

// P4: u in [0,768): v[b,d] = (1/16) qk[b,:]·WrT[d,:]
static __device__ void phase_v(int u, int tid,
                               const float* __restrict__ qk, const float* __restrict__ WrT,
                               float* __restrict__ vv) {
  int d0 = (u % 24) * 32;
  int b0 = (u / 24) * 3;
  int lane = tid & 63, wave = tid >> 6;
  float4 x[3][3];
#pragma unroll
  for (int bi = 0; bi < 3; ++bi)
#pragma unroll
    for (int jj = 0; jj < 3; ++jj)
      x[bi][jj] = ((const float4*)(qk + (size_t)(b0 + bi) * DD))[lane + 64 * jj];
  for (int i = 0; i < 8; ++i) {
    int d = d0 + wave * 8 + i;
    const float4* w4 = (const float4*)(WrT + (size_t)d * DD);
    float p[3] = {0.f, 0.f, 0.f};
#pragma unroll
    for (int jj = 0; jj < 3; ++jj) {
      float4 w = w4[lane + 64 * jj];
#pragma unroll
      for (int bi = 0; bi < 3; ++bi) p[bi] += dot4(w, x[bi][jj]);
    }
#pragma unroll
    for (int bi = 0; bi < 3; ++bi) {
      float pp = p[bi];
      for (int off = 32; off; off >>= 1) pp += __shfl_down(pp, off, 64);
      if (lane == 0) vv[(size_t)(b0 + bi) * DD + d] = pp * (1.f / 16.f);
    }
  }
}

// P5: u in [0,480): scores; b=u%96, hg=u/96 (20 h per unit)
static __device__ void phase_scores(int u, int tid,
                                    const float* __restrict__ hist, const float* __restrict__ vv,
                                    float* __restrict__ sc) {
  int b = u % 96, hg = u / 96;
  int lane = tid & 63, wave = tid >> 6;
  float4 v[3];
  const float4* vb = (const float4*)(vv + (size_t)b * DD);
#pragma unroll
  for (int jj = 0; jj < 3; ++jj) v[jj] = vb[lane + 64 * jj];
  const float* hb = hist + (size_t)b * HH * DD;
  for (int i = 0; i < 5; ++i) {
    int h = hg * 20 + wave * 5 + i;
    const float4* r = (const float4*)(hb + (size_t)h * DD);
    float p = 0.f;
#pragma unroll
    for (int jj = 0; jj < 3; ++jj) p += dot4(r[lane + 64 * jj], v[jj]);
    for (int off = 32; off; off >>= 1) p += __shfl_down(p, off, 64);
    if (lane == 0) sc[b * 128 + h] = p;
  }
}

// P6: u in [0,288): softmax (per block) + wsum; b=u%96, e=(u/96)*256+tid
// sal[0..99] = scores/alphas, sal[100] = 1/sum
static __device__ void phase_wsum(int u, int tid,
                                  const float* __restrict__ hist, const float* __restrict__ sc,
                                  float* __restrict__ wsum, float* sal) {
  int b = u % 96;
  int e = (u / 96) * 256 + tid;
  if (tid < HH) sal[tid] = sc[b * 128 + tid];
  __syncthreads();
  if (tid == 0) {
    float m = -1e30f;
    for (int h = 0; h < HH; ++h) m = fmaxf(m, sal[h]);
    float s = 0.f;
    for (int h = 0; h < HH; ++h) { float ex = __expf(sal[h] - m); sal[h] = ex; s += ex; }
    sal[100] = 1.f / s;
  }
  __syncthreads();
  float inv = sal[100];
  float acc = 0.f;
  const float* hb = hist + (size_t)b * HH * DD + e;
  for (int h = 0; h < HH; h += 4) {  // 100 % 4 == 0
    float v0 = hb[(size_t)(h + 0) * DD];
    float v1 = hb[(size_t)(h + 1) * DD];
    float v2 = hb[(size_t)(h + 2) * DD];
    float v3 = hb[(size_t)(h + 3) * DD];
    acc += sal[h + 0] * v0 + sal[h + 1] * v1 + sal[h + 2] * v2 + sal[h + 3] * v3;
  }
  wsum[(size_t)b * DD + e] = acc * inv;
  __syncthreads();  // sal reusable next iteration
}

// P7: u in [0,768): orow + 128-way broadcast write; uses sal[0..95] as stage
static __device__ void phase_orow(int u, int tid,
                                  const float* __restrict__ wsum, const float* __restrict__ Wr,
                                  const float* __restrict__ nl, float* __restrict__ out,
                                  float* sal) {
  int d0 = (u % 24) * 32;
  int b0 = (u / 24) * 3;
  int lane = tid & 63, wave = tid >> 6;
  float4 x[3][3];
#pragma unroll
  for (int bi = 0; bi < 3; ++bi)
#pragma unroll
    for (int jj = 0; jj < 3; ++jj)
      x[bi][jj] = ((const float4*)(wsum + (size_t)(b0 + bi) * DD))[lane + 64 * jj];
  for (int i = 0; i < 8; ++i) {
    int d = d0 + wave * 8 + i;
    const float4* w4 = (const float4*)(Wr + (size_t)d * DD);
    float p[3] = {0.f, 0.f, 0.f};
#pragma unroll
    for (int jj = 0; jj < 3; ++jj) {
      float4 w = w4[lane + 64 * jj];
#pragma unroll
      for (int bi = 0; bi < 3; ++bi) p[bi] += dot4(w, x[bi][jj]);
    }
#pragma unroll
    for (int bi = 0; bi < 3; ++bi) {
      float pp = p[bi];
      for (int off = 32; off; off >>= 1) pp += __shfl_down(pp, off, 64);
      if (lane == 0)
        sal[bi * 32 + wave * 8 + i] = pp + nl[(size_t)(b0 + bi) * DD + d];
    }
  }
  __syncthreads();
  // Broadcast: 3 b x 128 n x 8 float4 = 3072 float4 writes, 12 per thread.
  float4* out4 = (float4*)out;
  int d4 = d0 >> 2;
#pragma unroll
  for (int k = 0; k < 12; ++k) {
    int g = tid + (k << 8);
    int seg = g >> 3, off = g & 7;
    int bi = seg >> 7, n = seg & 127;
    float4 val = *(const float4*)&sal[bi * 32 + off * 4];
    out4[((size_t)(b0 + bi) * NN + n) * (DD / 4) + d4 + off] = val;
  }
  __syncthreads();  // sal reusable next iteration
}

// ===========================================================================
// Cooperative mega-kernel: 8 phases, 7 grid syncs, grid-stride over units
// ===========================================================================
__global__ void __launch_bounds__(256, 3)
mega(const float* __restrict__ hist, const float* __restrict__ Wl,
     const float* __restrict__ bl, const float* __restrict__ Wr,
     const float* __restrict__ WK, const float* __restrict__ WQ,
     const float* __restrict__ bQ,
     float* __restrict__ WrT, float* __restrict__ WKT, float* __restrict__ neigh,
     float* __restrict__ nl, float* __restrict__ u0, float* __restrict__ Qm,
     float* __restrict__ qk, float* __restrict__ vv, float* __restrict__ sc,
     float* __restrict__ wsum, float* __restrict__ out) {
  cg::grid_group grid = cg::this_grid();
  __shared__ __align__(16) float tile[32][33];
  __shared__ __align__(16) float sal[112];
  int tid = threadIdx.x;
  for (int u = blockIdx.x; u < 864; u += gridDim.x)
    phase_prep(u, tid, Wr, WK, hist, WrT, WKT, neigh, tile);
  grid.sync();
  for (int u = blockIdx.x; u < 768; u += gridDim.x)
    phase_nlu0(u, tid, neigh, hist, Wl, bl, Wr, nl, u0);
  grid.sync();
  for (int u = blockIdx.x; u < 256; u += gridDim.x)
    phase_q(u, tid, u0, WQ, bQ, Qm);
  grid.sync();
  for (int u = blockIdx.x; u < 768; u += gridDim.x)
    phase_qk(u, tid, Qm, WKT, qk);
  grid.sync();
  for (int u = blockIdx.x; u < 768; u += gridDim.x)
    phase_v(u, tid, qk, WrT, vv);
  grid.sync();
  for (int u = blockIdx.x; u < 480; u += gridDim.x)
    phase_scores(u, tid, hist, vv, sc);
  grid.sync();
  for (int u = blockIdx.x; u < 288; u += gridDim.x)
    phase_wsum(u, tid, hist, sc, wsum, sal);
  grid.sync();
  for (int u = blockIdx.x; u < 768; u += gridDim.x)
    phase_orow(u, tid, wsum, Wr, nl, out, sal);
}

// ===========================================================================
// Fallback per-phase kernels (used only if cooperative launch fails)
// ===========================================================================
__global__ void __launch_bounds__(256) f_prep(const float* Wr, const float* WK,
                                              const float* hist, float* WrT, float* WKT,
                                              float* neigh) {
  __shared__ __align__(16) float tile[32][33];
  phase_prep(blockIdx.x, threadIdx.x, Wr, WK, hist, WrT, WKT, neigh, tile);
}
__global__ void __launch_bounds__(256) f_nlu0(const float* neigh, const float* hist,
                                              const float* Wl, const float* bl,
                                              const float* Wr, float* nl, float* u0) {
  phase_nlu0(blockIdx.x, threadIdx.x, neigh, hist, Wl, bl, Wr, nl, u0);
}
__global__ void __launch_bounds__(256) f_q(const float* u0, const float* WQ,
                                           const float* bQ, float* Qm) {
  phase_q(blockIdx.x, threadIdx.x, u0, WQ, bQ, Qm);
}
__global__ void __launch_bounds__(256) f_qk(const float* Qm, const float* WKT, float* qk) {
  phase_qk(blockIdx.x, threadIdx.x, Qm, WKT, qk);
}
__global__ void __launch_bounds__(256) f_v(const float* qk, const float* WrT, float* vv) {
  phase_v(blockIdx.x, threadIdx.x, qk, WrT, vv);
}
__global__ void __launch_bounds__(256) f_scores(const float* hist, const float* vv, float* sc) {
  phase_scores(blockIdx.x, threadIdx.x, hist, vv, sc);
}
__global__ void __launch_bounds__(256) f_wsum(const float* hist, const float* sc, float* wsum) {
  __shared__ __align__(16) float sal[112];
  phase_wsum(blockIdx.x, threadIdx.x, hist, sc, wsum, sal);
}
__global__ void __launch_bounds__(256) f_orow(const float* wsum, const float* Wr,
                                              const float* nl, float* out) {
  __shared__ __align__(16) float sal[112];
  phase_orow(blockIdx.x, threadIdx.x, wsum, Wr, nl, out, sal);
}

// ===========================================================================
extern "C" void kernel_launch(void* const* d_in, const int* in_sizes, int n_in,
                              void* d_out, int out_size, void* d_ws, size_t ws_size,
                              hipStream_t stream) {
  const float *hist = nullptr, *Wl = nullptr, *Wr = nullptr, *WK = nullptr,
              *WQ = nullptr, *bl = nullptr, *bQ = nullptr;
  int seenDxD = 0, seenAxD = 0;
  for (int i = 0; i < n_in; ++i) {
    int s = in_sizes[i];
    const float* p = (const float*)d_in[i];
    if (s == BB * HH * DD) hist = p;
    else if (s == BB * NN * DD) { /* candidate — unused */ }
    else if (s == DD * DD) { if (seenDxD++ == 0) Wl = p; else Wr = p; }
    else if (s == AA * DD) { if (seenAxD++ == 0) WK = p; else WQ = p; }
    else if (s == DD) bl = p;
    else if (s == AA) bQ = p;
  }

  float* ws = (float*)d_ws;
  float* WrT   = ws + 0;         // 589824
  float* WKT   = ws + 589824;    // 196608
  float* neigh = ws + 786432;    // 73728
  float* nl    = ws + 860160;    // 73728
  float* u0v   = ws + 933888;    // 73728
  float* Qm    = ws + 1007616;   // 24576
  float* qk    = ws + 1032192;   // 73728
  float* vv    = ws + 1105920;   // 73728
  float* sc    = ws + 1179648;   // 12288
  float* wsumv = ws + 1191936;   // 73728  -> total ~5.1 MB
  float* outp  = (float*)d_out;

  // Cooperative grid: clamp to guaranteed co-residency (256 CUs on gfx950).
  int maxPerCU = 0;
  hipError_t qerr = hipOccupancyMaxActiveBlocksPerMultiprocessor(&maxPerCU, mega, 256, 0);
  int grid = 768;
  if (qerr == hipSuccess && maxPerCU >= 1) {
    int cap = maxPerCU * 256;
    if (cap < grid) grid = cap;
  } else {
    grid = 512;  // conservative: 2 blocks/CU co-resident at any plausible VGPR
  }

  void* args[] = {(void*)&hist, (void*)&Wl, (void*)&bl, (void*)&Wr, (void*)&WK,
                  (void*)&WQ, (void*)&bQ, (void*)&WrT, (void*)&WKT, (void*)&neigh,
                  (void*)&nl, (void*)&u0v, (void*)&Qm, (void*)&qk, (void*)&vv,
                  (void*)&sc, (void*)&wsumv, (void*)&outp};
  hipError_t lerr = hipLaunchCooperativeKernel((const void*)mega, dim3(grid), dim3(256),
                                               args, 0, stream);
  if (lerr != hipSuccess) {
    // Fallback: proven 8-kernel chain (round-7 structure, flat grids)
    f_prep  <<<dim3(864), dim3(256), 0, stream>>>(Wr, WK, hist, WrT, WKT, neigh);
    f_nlu0  <<<dim3(768), dim3(256), 0, stream>>>(neigh, hist, Wl, bl, Wr, nl, u0v);
    f_q     <<<dim3(256), dim3(256), 0, stream>>>(u0v, WQ, bQ, Qm);
    f_qk    <<<dim3(768), dim3(256), 0, stream>>>(Qm, WKT, qk);
    f_v     <<<dim3(768), dim3(256), 0, stream>>>(qk, WrT, vv);
    f_scores<<<dim3(480), dim3(256), 0, stream>>>(hist, vv, sc);
    f_wsum  <<<dim3(288), dim3(256), 0, stream>>>(hist, sc, wsumv);
    f_orow  <<<dim3(768), dim3(256), 0, stream>>>(wsumv, Wr, nl, outp);
  }
}

// Round 9
// 111.322 us; speedup vs baseline: 3.1974x; 3.1974x over previous
//
#include <hip/hip_runtime.h>
#include <hip/hip_bf16.h>

// Problem constants
#define BB 96    // batch
#define HH 100   // history length
#define NN 128   // candidates (broadcast only)
#define DD 768   // embed dim
#define AA 256   // attention dim

static __device__ __forceinline__ float dot4(float4 a, float4 b) {
  return a.x * b.x + a.y * b.y + a.z * b.z + a.w * b.w;
}

// ---------------------------------------------------------------------------
// D1 k_prep (288 blocks):
//   blocks [0,192)   : MT[d,a] = sum_e WK[a,e]*Wr[e,d]  (LDS-tiled GEMM,
//                      32x32 output tiles; 24 d-tiles x 8 a-tiles)
//   blocks [192,288) : neigh[b,d] = mean_{h<96} hist[b,h,d]  (1 block/b)
// MT replaces both the WrT and WKT transposes: v = Q @ (WK@Wr) / 16.
// ---------------------------------------------------------------------------
__global__ void __launch_bounds__(256)
k_prep(const float* __restrict__ Wr, const float* __restrict__ WK,
       const float* __restrict__ hist,
       float* __restrict__ MT, float* __restrict__ neigh) {
  __shared__ float sWr[32][33];  // [e][d]
  __shared__ float sWK[32][33];  // [a][e]
  int bid = blockIdx.x;
  int tid = threadIdx.x;
  if (bid < 192) {
    int d0 = (bid % 24) * 32;
    int a0 = (bid / 24) * 32;
    int tx = tid & 31, ty = tid >> 5;  // 32 x 8
    float acc[4] = {0.f, 0.f, 0.f, 0.f};
    for (int e0 = 0; e0 < DD; e0 += 32) {
#pragma unroll
      for (int k = 0; k < 4; ++k) {
        sWr[ty + 8 * k][tx] = Wr[(size_t)(e0 + ty + 8 * k) * DD + d0 + tx];
        sWK[ty + 8 * k][tx] = WK[(size_t)(a0 + ty + 8 * k) * DD + e0 + tx];
      }
      __syncthreads();
#pragma unroll 8
      for (int e = 0; e < 32; ++e) {
        float w = sWr[e][tx];
#pragma unroll
        for (int k = 0; k < 4; ++k) acc[k] += w * sWK[ty + 8 * k][e];
      }
      __syncthreads();
    }
#pragma unroll
    for (int k = 0; k < 4; ++k)
      MT[(size_t)(d0 + tx) * AA + a0 + ty + 8 * k] = acc[k];
  } else {
    int b = bid - 192;
    if (tid < 192) {  // 192 float4 = 768 floats
      const float* hb = hist + (size_t)b * HH * DD + tid * 4;
      float4 a0 = make_float4(0.f, 0.f, 0.f, 0.f);
      float4 a1 = make_float4(0.f, 0.f, 0.f, 0.f);
#pragma unroll 8
      for (int h = 0; h < 96; h += 2) {
        float4 x = *(const float4*)(hb + (size_t)h * DD);
        float4 y = *(const float4*)(hb + (size_t)(h + 1) * DD);
        a0.x += x.x; a0.y += x.y; a0.z += x.z; a0.w += x.w;
        a1.x += y.x; a1.y += y.y; a1.z += y.z; a1.w += y.w;
      }
      float4 m = make_float4((a0.x + a1.x) * (1.f / 96.f), (a0.y + a1.y) * (1.f / 96.f),
                             (a0.z + a1.z) * (1.f / 96.f), (a0.w + a1.w) * (1.f / 96.f));
      *(float4*)(neigh + (size_t)b * DD + tid * 4) = m;
    }
  }
}

// ---------------------------------------------------------------------------
// D2 k_nl_u0: nl[b,e] = neigh[b,:]·W_l[e,:] + b_l[e];
//             u0[b,e] = hist[b,0,:]·W_r[e,:] + nl[b,e]
// wave-split-K, 3 b/thread, 32 e/block, grid (24, 32)
// ---------------------------------------------------------------------------
__global__ void k_nl_u0(const float* __restrict__ neigh, const float* __restrict__ hist,
                        const float* __restrict__ Wl, const float* __restrict__ bl,
                        const float* __restrict__ Wr,
                        float* __restrict__ nl, float* __restrict__ u0) {
  int e0 = blockIdx.x * 32;
  int b0 = blockIdx.y * 3;
  int lane = threadIdx.x & 63, wave = threadIdx.x >> 6;
  float4 xn[3][3], xh[3][3];
#pragma unroll
  for (int bi = 0; bi < 3; ++bi) {
    int b = b0 + bi;
#pragma unroll
    for (int jj = 0; jj < 3; ++jj) {
      int idx = lane + 64 * jj;
      xn[bi][jj] = ((const float4*)(neigh + (size_t)b * DD))[idx];
      xh[bi][jj] = ((const float4*)(hist + (size_t)b * HH * DD))[idx];  // h=0 row
    }
  }
  for (int i = 0; i < 8; ++i) {
    int e = e0 + wave * 8 + i;
    const float4* wl4 = (const float4*)(Wl + (size_t)e * DD);
    const float4* wr4 = (const float4*)(Wr + (size_t)e * DD);
    float pl[3] = {0.f, 0.f, 0.f}, pr[3] = {0.f, 0.f, 0.f};
#pragma unroll
    for (int jj = 0; jj < 3; ++jj) {
      float4 wl = wl4[lane + 64 * jj];
      float4 wr = wr4[lane + 64 * jj];
#pragma unroll
      for (int bi = 0; bi < 3; ++bi) {
        pl[bi] += dot4(wl, xn[bi][jj]);
        pr[bi] += dot4(wr, xh[bi][jj]);
      }
    }
#pragma unroll
    for (int bi = 0; bi < 3; ++bi) {
      float pp = pl[bi], qq = pr[bi];
      for (int off = 32; off; off >>= 1) {
        pp += __shfl_down(pp, off, 64);
        qq += __shfl_down(qq, off, 64);
      }
      if (lane == 0) {
        float nle = pp + bl[e];
        nl[(size_t)(b0 + bi) * DD + e] = nle;
        u0[(size_t)(b0 + bi) * DD + e] = qq + nle;
      }
    }
  }
}

// ---------------------------------------------------------------------------
// D3 k_q: Q[b,a] = u0[b,:]·W_Q[a,:] + b_Q[a]   grid (8, 32)
// ---------------------------------------------------------------------------
__global__ void k_q(const float* __restrict__ u0, const float* __restrict__ WQ,
                    const float* __restrict__ bQ, float* __restrict__ Qm) {
  int a0 = blockIdx.x * 32;
  int b0 = blockIdx.y * 3;
  int lane = threadIdx.x & 63, wave = threadIdx.x >> 6;
  float4 x[3][3];
#pragma unroll
  for (int bi = 0; bi < 3; ++bi)
#pragma unroll
    for (int jj = 0; jj < 3; ++jj)
      x[bi][jj] = ((const float4*)(u0 + (size_t)(b0 + bi) * DD))[lane + 64 * jj];
  for (int i = 0; i < 8; ++i) {
    int a = a0 + wave * 8 + i;
    const float4* w4 = (const float4*)(WQ + (size_t)a * DD);
    float p[3] = {0.f, 0.f, 0.f};
#pragma unroll
    for (int jj = 0; jj < 3; ++jj) {
      float4 w = w4[lane + 64 * jj];
#pragma unroll
      for (int bi = 0; bi < 3; ++bi) p[bi] += dot4(w, x[bi][jj]);
    }
#pragma unroll
    for (int bi = 0; bi < 3; ++bi) {
      float pp = p[bi];
      for (int off = 32; off; off >>= 1) pp += __shfl_down(pp, off, 64);
      if (lane == 0) Qm[(size_t)(b0 + bi) * AA + a] = pp + bQ[a];
    }
  }
}

// ---------------------------------------------------------------------------
// D4 k_v: v[b,d] = (1/16) * Q[b,:]·MT[d,:]   grid (24, 32)   (K = 256)
// ---------------------------------------------------------------------------
__global__ void k_v(const float* __restrict__ Qm, const float* __restrict__ MT,
                    float* __restrict__ vv) {
  int d0 = blockIdx.x * 32;
  int b0 = blockIdx.y * 3;
  int lane = threadIdx.x & 63, wave = threadIdx.x >> 6;
  float4 x[3];
#pragma unroll
  for (int bi = 0; bi < 3; ++bi)
    x[bi] = ((const float4*)(Qm + (size_t)(b0 + bi) * AA))[lane];
  for (int i = 0; i < 8; ++i) {
    int d = d0 + wave * 8 + i;
    float4 w = ((const float4*)(MT + (size_t)d * AA))[lane];
    float p[3];
#pragma unroll
    for (int bi = 0; bi < 3; ++bi) p[bi] = dot4(w, x[bi]);
#pragma unroll
    for (int bi = 0; bi < 3; ++bi) {
      float pp = p[bi];
      for (int off = 32; off; off >>= 1) pp += __shfl_down(pp, off, 64);
      if (lane == 0) vv[(size_t)(b0 + bi) * DD + d] = pp * (1.f / 16.f);
    }
  }
}

// ---------------------------------------------------------------------------
// D5 k_attn: fused scores -> softmax -> wsum.  grid (96, 3), 256 threads.
// Each block: full scores for its b (4 waves x 25 h, hist L3-warm),
// wave-0 parallel softmax, then wsum for its 256-col e-slice.
// ---------------------------------------------------------------------------
__global__ void __launch_bounds__(256)
k_attn(const float* __restrict__ hist, const float* __restrict__ vv,
       float* __restrict__ wsum) {
  int b = blockIdx.x;
  int es = blockIdx.y;
  int tid = threadIdx.x, lane = tid & 63, wave = tid >> 6;
  __shared__ __align__(16) float sv[DD];
  __shared__ float sal[HH];
  if (tid < 192)
    ((float4*)sv)[tid] = ((const float4*)(vv + (size_t)b * DD))[tid];
  __syncthreads();
  // scores: 4 waves x 25 h
  {
    float4 v0 = ((const float4*)sv)[lane];
    float4 v1 = ((const float4*)sv)[lane + 64];
    float4 v2 = ((const float4*)sv)[lane + 128];
    const float* hb = hist + (size_t)b * HH * DD;
    for (int i = 0; i < 25; ++i) {
      int h = wave * 25 + i;
      const float4* r = (const float4*)(hb + (size_t)h * DD);
      float p = dot4(r[lane], v0) + dot4(r[lane + 64], v1) + dot4(r[lane + 128], v2);
      for (int off = 32; off; off >>= 1) p += __shfl_down(p, off, 64);
      if (lane == 0) sal[h] = p;
    }
  }
  __syncthreads();
  // softmax over 100 (wave 0; lanes hold h=lane and h=lane+64)
  if (wave == 0) {
    float x0 = (lane < HH) ? sal[lane] : -1e30f;
    float x1 = (lane + 64 < HH) ? sal[lane + 64] : -1e30f;
    float m = fmaxf(x0, x1);
    for (int off = 32; off; off >>= 1) m = fmaxf(m, __shfl_xor(m, off, 64));
    float e0 = (lane < HH) ? __expf(x0 - m) : 0.f;
    float e1 = (lane + 64 < HH) ? __expf(x1 - m) : 0.f;
    float s = e0 + e1;
    for (int off = 32; off; off >>= 1) s += __shfl_xor(s, off, 64);
    float inv = 1.f / s;
    if (lane < HH) sal[lane] = e0 * inv;
    if (lane + 64 < HH) sal[lane + 64] = e1 * inv;
  }
  __syncthreads();
  // wsum for this block's 256-col slice
  {
    int e = es * 256 + tid;
    const float* hb = hist + (size_t)b * HH * DD + e;
    float acc = 0.f;
    for (int h = 0; h < HH; h += 4) {  // 100 % 4 == 0
      float v0 = hb[(size_t)(h + 0) * DD];
      float v1 = hb[(size_t)(h + 1) * DD];
      float v2 = hb[(size_t)(h + 2) * DD];
      float v3 = hb[(size_t)(h + 3) * DD];
      acc += sal[h + 0] * v0 + sal[h + 1] * v1 + sal[h + 2] * v2 + sal[h + 3] * v3;
    }
    wsum[(size_t)b * DD + e] = acc;
  }
}

// ---------------------------------------------------------------------------
// D6 k_orow_write: orow[b,d] = nl[b,d] + wsum[b,:]·W_r[d,:], then broadcast
// directly to out[b, 0..127, d] (via LDS stage). grid (24, 32).
// ---------------------------------------------------------------------------
__global__ void k_orow_write(const float* __restrict__ wsum, const float* __restrict__ Wr,
                             const float* __restrict__ nl, float* __restrict__ out) {
  int d0 = blockIdx.x * 32;
  int b0 = blockIdx.y * 3;
  int lane = threadIdx.x & 63, wave = threadIdx.x >> 6;
  __shared__ __align__(16) float s_o[3][32];
  float4 x[3][3];
#pragma unroll
  for (int bi = 0; bi < 3; ++bi)
#pragma unroll
    for (int jj = 0; jj < 3; ++jj)
      x[bi][jj] = ((const float4*)(wsum + (size_t)(b0 + bi) * DD))[lane + 64 * jj];
  for (int i = 0; i < 8; ++i) {
    int d = d0 + wave * 8 + i;
    const float4* w4 = (const float4*)(Wr + (size_t)d * DD);
    float p[3] = {0.f, 0.f, 0.f};
#pragma unroll
    for (int jj = 0; jj < 3; ++jj) {
      float4 w = w4[lane + 64 * jj];
#pragma unroll
      for (int bi = 0; bi < 3; ++bi) p[bi] += dot4(w, x[bi][jj]);
    }
#pragma unroll
    for (int bi = 0; bi < 3; ++bi) {
      float pp = p[bi];
      for (int off = 32; off; off >>= 1) pp += __shfl_down(pp, off, 64);
      if (lane == 0)
        s_o[bi][wave * 8 + i] = pp + nl[(size_t)(b0 + bi) * DD + d];
    }
  }
  __syncthreads();
  // Broadcast: 3 b x 128 n x 8 float4 = 3072 float4 writes, 12 per thread.
  float4* out4 = (float4*)out;
  int d4 = d0 >> 2;
#pragma unroll
  for (int k = 0; k < 12; ++k) {
    int g = threadIdx.x + (k << 8);
    int seg = g >> 3, off = g & 7;
    int bi = seg >> 7, n = seg & 127;
    float4 val = *(const float4*)&s_o[bi][off * 4];
    out4[((size_t)(b0 + bi) * NN + n) * (DD / 4) + d4 + off] = val;
  }
}

// ---------------------------------------------------------------------------
extern "C" void kernel_launch(void* const* d_in, const int* in_sizes, int n_in,
                              void* d_out, int out_size, void* d_ws, size_t ws_size,
                              hipStream_t stream) {
  const float *hist = nullptr, *Wl = nullptr, *Wr = nullptr, *WK = nullptr,
              *WQ = nullptr, *bl = nullptr, *bQ = nullptr;
  int seenDxD = 0, seenAxD = 0;
  for (int i = 0; i < n_in; ++i) {
    int s = in_sizes[i];
    const float* p = (const float*)d_in[i];
    if (s == BB * HH * DD) hist = p;
    else if (s == BB * NN * DD) { /* candidate — unused */ }
    else if (s == DD * DD) { if (seenDxD++ == 0) Wl = p; else Wr = p; }
    else if (s == AA * DD) { if (seenAxD++ == 0) WK = p; else WQ = p; }
    else if (s == DD) bl = p;
    else if (s == AA) bQ = p;
  }

  float* ws = (float*)d_ws;
  float* MT    = ws + 0;         // 768*256 = 196608
  float* neigh = ws + 196608;    // 73728
  float* nl    = ws + 270336;    // 73728
  float* u0    = ws + 344064;    // 73728
  float* Qm    = ws + 417792;    // 24576
  float* vv    = ws + 442368;    // 73728
  float* wsum  = ws + 516096;    // 73728  -> total ~2.4 MB
  float* out = (float*)d_out;

  k_prep      <<<dim3(288),    dim3(256), 0, stream>>>(Wr, WK, hist, MT, neigh);
  k_nl_u0     <<<dim3(24, 32), dim3(256), 0, stream>>>(neigh, hist, Wl, bl, Wr, nl, u0);
  k_q         <<<dim3(8, 32),  dim3(256), 0, stream>>>(u0, WQ, bQ, Qm);
  k_v         <<<dim3(24, 32), dim3(256), 0, stream>>>(Qm, MT, vv);
  k_attn      <<<dim3(96, 3),  dim3(256), 0, stream>>>(hist, vv, wsum);
  k_orow_write<<<dim3(24, 32), dim3(256), 0, stream>>>(wsum, Wr, nl, out);
}

// Round 10
// 94.004 us; speedup vs baseline: 3.7864x; 1.1842x over previous
//
#include <hip/hip_runtime.h>
#include <hip/hip_bf16.h>

// Problem constants
#define BB 96    // batch
#define HH 100   // history length
#define NN 128   // candidates (broadcast only)
#define DD 768   // embed dim
#define AA 256   // attention dim

static __device__ __forceinline__ float dot4(float4 a, float4 b) {
  return a.x * b.x + a.y * b.y + a.z * b.z + a.w * b.w;
}

// ---------------------------------------------------------------------------
// D1 k_prep (864 blocks):
//   blocks [0,768)   : MTp[s][d,a] = sum_{e in slab s} WK[a,e]*Wr[e,d]
//                      split-K GEMM: 4 slabs x 192 output tiles (32x32),
//                      6 K-tiles of 32 each — short loops, 3 blocks/CU.
//   blocks [768,864) : neigh[b,d] = mean_{h<96} hist[b,h,d]  (1 block/b)
// MT = sum_s MTp[s] replaces both transposes: v = Q @ (WK@Wr) / 16.
// ---------------------------------------------------------------------------
__global__ void __launch_bounds__(256)
k_prep(const float* __restrict__ Wr, const float* __restrict__ WK,
       const float* __restrict__ hist,
       float* __restrict__ MTp, float* __restrict__ neigh) {
  __shared__ float sWr[32][33];  // [e][d]
  __shared__ float sWK[32][33];  // [a][e]
  int bid = blockIdx.x;
  int tid = threadIdx.x;
  if (bid < 768) {
    int s = bid / 192;           // K-slab 0..3  (e in [s*192, s*192+192))
    int t = bid % 192;
    int d0 = (t % 24) * 32;
    int a0 = (t / 24) * 32;
    int tx = tid & 31, ty = tid >> 5;  // 32 x 8
    float acc[4] = {0.f, 0.f, 0.f, 0.f};
    int ebase = s * 192;
    for (int e0 = ebase; e0 < ebase + 192; e0 += 32) {
#pragma unroll
      for (int k = 0; k < 4; ++k) {
        sWr[ty + 8 * k][tx] = Wr[(size_t)(e0 + ty + 8 * k) * DD + d0 + tx];
        sWK[ty + 8 * k][tx] = WK[(size_t)(a0 + ty + 8 * k) * DD + e0 + tx];
      }
      __syncthreads();
#pragma unroll 8
      for (int e = 0; e < 32; ++e) {
        float w = sWr[e][tx];
#pragma unroll
        for (int k = 0; k < 4; ++k) acc[k] += w * sWK[ty + 8 * k][e];
      }
      __syncthreads();
    }
    float* MTs = MTp + (size_t)s * (DD * AA);
#pragma unroll
    for (int k = 0; k < 4; ++k)
      MTs[(size_t)(d0 + tx) * AA + a0 + ty + 8 * k] = acc[k];
  } else {
    int b = bid - 768;
    if (tid < 192) {  // 192 float4 = 768 floats
      const float* hb = hist + (size_t)b * HH * DD + tid * 4;
      float4 a0 = make_float4(0.f, 0.f, 0.f, 0.f);
      float4 a1 = make_float4(0.f, 0.f, 0.f, 0.f);
#pragma unroll 8
      for (int h = 0; h < 96; h += 2) {
        float4 x = *(const float4*)(hb + (size_t)h * DD);
        float4 y = *(const float4*)(hb + (size_t)(h + 1) * DD);
        a0.x += x.x; a0.y += x.y; a0.z += x.z; a0.w += x.w;
        a1.x += y.x; a1.y += y.y; a1.z += y.z; a1.w += y.w;
      }
      float4 m = make_float4((a0.x + a1.x) * (1.f / 96.f), (a0.y + a1.y) * (1.f / 96.f),
                             (a0.z + a1.z) * (1.f / 96.f), (a0.w + a1.w) * (1.f / 96.f));
      *(float4*)(neigh + (size_t)b * DD + tid * 4) = m;
    }
  }
}

// ---------------------------------------------------------------------------
// D2 k_nl_u0: nl[b,e] = neigh[b,:]·W_l[e,:] + b_l[e];
//             u0[b,e] = hist[b,0,:]·W_r[e,:] + nl[b,e]
// wave-split-K, 3 b/thread, 32 e/block, grid (24, 32)
// ---------------------------------------------------------------------------
__global__ void k_nl_u0(const float* __restrict__ neigh, const float* __restrict__ hist,
                        const float* __restrict__ Wl, const float* __restrict__ bl,
                        const float* __restrict__ Wr,
                        float* __restrict__ nl, float* __restrict__ u0) {
  int e0 = blockIdx.x * 32;
  int b0 = blockIdx.y * 3;
  int lane = threadIdx.x & 63, wave = threadIdx.x >> 6;
  float4 xn[3][3], xh[3][3];
#pragma unroll
  for (int bi = 0; bi < 3; ++bi) {
    int b = b0 + bi;
#pragma unroll
    for (int jj = 0; jj < 3; ++jj) {
      int idx = lane + 64 * jj;
      xn[bi][jj] = ((const float4*)(neigh + (size_t)b * DD))[idx];
      xh[bi][jj] = ((const float4*)(hist + (size_t)b * HH * DD))[idx];  // h=0 row
    }
  }
  for (int i = 0; i < 8; ++i) {
    int e = e0 + wave * 8 + i;
    const float4* wl4 = (const float4*)(Wl + (size_t)e * DD);
    const float4* wr4 = (const float4*)(Wr + (size_t)e * DD);
    float pl[3] = {0.f, 0.f, 0.f}, pr[3] = {0.f, 0.f, 0.f};
#pragma unroll
    for (int jj = 0; jj < 3; ++jj) {
      float4 wl = wl4[lane + 64 * jj];
      float4 wr = wr4[lane + 64 * jj];
#pragma unroll
      for (int bi = 0; bi < 3; ++bi) {
        pl[bi] += dot4(wl, xn[bi][jj]);
        pr[bi] += dot4(wr, xh[bi][jj]);
      }
    }
#pragma unroll
    for (int bi = 0; bi < 3; ++bi) {
      float pp = pl[bi], qq = pr[bi];
      for (int off = 32; off; off >>= 1) {
        pp += __shfl_down(pp, off, 64);
        qq += __shfl_down(qq, off, 64);
      }
      if (lane == 0) {
        float nle = pp + bl[e];
        nl[(size_t)(b0 + bi) * DD + e] = nle;
        u0[(size_t)(b0 + bi) * DD + e] = qq + nle;
      }
    }
  }
}

// ---------------------------------------------------------------------------
// D3 k_q: Q[b,a] = u0[b,:]·W_Q[a,:] + b_Q[a]   grid (8, 32)
// ---------------------------------------------------------------------------
__global__ void k_q(const float* __restrict__ u0, const float* __restrict__ WQ,
                    const float* __restrict__ bQ, float* __restrict__ Qm) {
  int a0 = blockIdx.x * 32;
  int b0 = blockIdx.y * 3;
  int lane = threadIdx.x & 63, wave = threadIdx.x >> 6;
  float4 x[3][3];
#pragma unroll
  for (int bi = 0; bi < 3; ++bi)
#pragma unroll
    for (int jj = 0; jj < 3; ++jj)
      x[bi][jj] = ((const float4*)(u0 + (size_t)(b0 + bi) * DD))[lane + 64 * jj];
  for (int i = 0; i < 8; ++i) {
    int a = a0 + wave * 8 + i;
    const float4* w4 = (const float4*)(WQ + (size_t)a * DD);
    float p[3] = {0.f, 0.f, 0.f};
#pragma unroll
    for (int jj = 0; jj < 3; ++jj) {
      float4 w = w4[lane + 64 * jj];
#pragma unroll
      for (int bi = 0; bi < 3; ++bi) p[bi] += dot4(w, x[bi][jj]);
    }
#pragma unroll
    for (int bi = 0; bi < 3; ++bi) {
      float pp = p[bi];
      for (int off = 32; off; off >>= 1) pp += __shfl_down(pp, off, 64);
      if (lane == 0) Qm[(size_t)(b0 + bi) * AA + a] = pp + bQ[a];
    }
  }
}

// ---------------------------------------------------------------------------
// D4 k_v: v[b,d] = (1/16) * Q[b,:]·(sum_s MTp[s][d,:])   grid (24, 32)
// ---------------------------------------------------------------------------
__global__ void k_v(const float* __restrict__ Qm, const float* __restrict__ MTp,
                    float* __restrict__ vv) {
  int d0 = blockIdx.x * 32;
  int b0 = blockIdx.y * 3;
  int lane = threadIdx.x & 63, wave = threadIdx.x >> 6;
  float4 x[3];
#pragma unroll
  for (int bi = 0; bi < 3; ++bi)
    x[bi] = ((const float4*)(Qm + (size_t)(b0 + bi) * AA))[lane];
  for (int i = 0; i < 8; ++i) {
    int d = d0 + wave * 8 + i;
    float4 w0 = ((const float4*)(MTp + 0 * (size_t)(DD * AA) + (size_t)d * AA))[lane];
    float4 w1 = ((const float4*)(MTp + 1 * (size_t)(DD * AA) + (size_t)d * AA))[lane];
    float4 w2 = ((const float4*)(MTp + 2 * (size_t)(DD * AA) + (size_t)d * AA))[lane];
    float4 w3 = ((const float4*)(MTp + 3 * (size_t)(DD * AA) + (size_t)d * AA))[lane];
    float4 w = make_float4(w0.x + w1.x + w2.x + w3.x, w0.y + w1.y + w2.y + w3.y,
                           w0.z + w1.z + w2.z + w3.z, w0.w + w1.w + w2.w + w3.w);
    float p[3];
#pragma unroll
    for (int bi = 0; bi < 3; ++bi) p[bi] = dot4(w, x[bi]);
#pragma unroll
    for (int bi = 0; bi < 3; ++bi) {
      float pp = p[bi];
      for (int off = 32; off; off >>= 1) pp += __shfl_down(pp, off, 64);
      if (lane == 0) vv[(size_t)(b0 + bi) * DD + d] = pp * (1.f / 16.f);
    }
  }
}

// ---------------------------------------------------------------------------
// D5 k_attn: fused scores -> softmax -> wsum.  grid (96, 3), 256 threads.
// ---------------------------------------------------------------------------
__global__ void __launch_bounds__(256)
k_attn(const float* __restrict__ hist, const float* __restrict__ vv,
       float* __restrict__ wsum) {
  int b = blockIdx.x;
  int es = blockIdx.y;
  int tid = threadIdx.x, lane = tid & 63, wave = tid >> 6;
  __shared__ __align__(16) float sv[DD];
  __shared__ float sal[HH];
  if (tid < 192)
    ((float4*)sv)[tid] = ((const float4*)(vv + (size_t)b * DD))[tid];
  __syncthreads();
  // scores: 4 waves x 25 h
  {
    float4 v0 = ((const float4*)sv)[lane];
    float4 v1 = ((const float4*)sv)[lane + 64];
    float4 v2 = ((const float4*)sv)[lane + 128];
    const float* hb = hist + (size_t)b * HH * DD;
    for (int i = 0; i < 25; ++i) {
      int h = wave * 25 + i;
      const float4* r = (const float4*)(hb + (size_t)h * DD);
      float p = dot4(r[lane], v0) + dot4(r[lane + 64], v1) + dot4(r[lane + 128], v2);
      for (int off = 32; off; off >>= 1) p += __shfl_down(p, off, 64);
      if (lane == 0) sal[h] = p;
    }
  }
  __syncthreads();
  // softmax over 100 (wave 0; lanes hold h=lane and h=lane+64)
  if (wave == 0) {
    float x0 = (lane < HH) ? sal[lane] : -1e30f;
    float x1 = (lane + 64 < HH) ? sal[lane + 64] : -1e30f;
    float m = fmaxf(x0, x1);
    for (int off = 32; off; off >>= 1) m = fmaxf(m, __shfl_xor(m, off, 64));
    float e0 = (lane < HH) ? __expf(x0 - m) : 0.f;
    float e1 = (lane + 64 < HH) ? __expf(x1 - m) : 0.f;
    float s = e0 + e1;
    for (int off = 32; off; off >>= 1) s += __shfl_xor(s, off, 64);
    float inv = 1.f / s;
    if (lane < HH) sal[lane] = e0 * inv;
    if (lane + 64 < HH) sal[lane + 64] = e1 * inv;
  }
  __syncthreads();
  // wsum for this block's 256-col slice
  {
    int e = es * 256 + tid;
    const float* hb = hist + (size_t)b * HH * DD + e;
    float acc = 0.f;
    for (int h = 0; h < HH; h += 4) {  // 100 % 4 == 0
      float v0 = hb[(size_t)(h + 0) * DD];
      float v1 = hb[(size_t)(h + 1) * DD];
      float v2 = hb[(size_t)(h + 2) * DD];
      float v3 = hb[(size_t)(h + 3) * DD];
      acc += sal[h + 0] * v0 + sal[h + 1] * v1 + sal[h + 2] * v2 + sal[h + 3] * v3;
    }
    wsum[(size_t)b * DD + e] = acc;
  }
}

// ---------------------------------------------------------------------------
// D6 k_orow_write: orow[b,d] = nl[b,d] + wsum[b,:]·W_r[d,:], then broadcast
// directly to out[b, 0..127, d] (via LDS stage). grid (24, 32).
// ---------------------------------------------------------------------------
__global__ void k_orow_write(const float* __restrict__ wsum, const float* __restrict__ Wr,
                             const float* __restrict__ nl, float* __restrict__ out) {
  int d0 = blockIdx.x * 32;
  int b0 = blockIdx.y * 3;
  int lane = threadIdx.x & 63, wave = threadIdx.x >> 6;
  __shared__ __align__(16) float s_o[3][32];
  float4 x[3][3];
#pragma unroll
  for (int bi = 0; bi < 3; ++bi)
#pragma unroll
    for (int jj = 0; jj < 3; ++jj)
      x[bi][jj] = ((const float4*)(wsum + (size_t)(b0 + bi) * DD))[lane + 64 * jj];
  for (int i = 0; i < 8; ++i) {
    int d = d0 + wave * 8 + i;
    const float4* w4 = (const float4*)(Wr + (size_t)d * DD);
    float p[3] = {0.f, 0.f, 0.f};
#pragma unroll
    for (int jj = 0; jj < 3; ++jj) {
      float4 w = w4[lane + 64 * jj];
#pragma unroll
      for (int bi = 0; bi < 3; ++bi) p[bi] += dot4(w, x[bi][jj]);
    }
#pragma unroll
    for (int bi = 0; bi < 3; ++bi) {
      float pp = p[bi];
      for (int off = 32; off; off >>= 1) pp += __shfl_down(pp, off, 64);
      if (lane == 0)
        s_o[bi][wave * 8 + i] = pp + nl[(size_t)(b0 + bi) * DD + d];
    }
  }
  __syncthreads();
  // Broadcast: 3 b x 128 n x 8 float4 = 3072 float4 writes, 12 per thread.
  float4* out4 = (float4*)out;
  int d4 = d0 >> 2;
#pragma unroll
  for (int k = 0; k < 12; ++k) {
    int g = threadIdx.x + (k << 8);
    int seg = g >> 3, off = g & 7;
    int bi = seg >> 7, n = seg & 127;
    float4 val = *(const float4*)&s_o[bi][off * 4];
    out4[((size_t)(b0 + bi) * NN + n) * (DD / 4) + d4 + off] = val;
  }
}

// ---------------------------------------------------------------------------
extern "C" void kernel_launch(void* const* d_in, const int* in_sizes, int n_in,
                              void* d_out, int out_size, void* d_ws, size_t ws_size,
                              hipStream_t stream) {
  const float *hist = nullptr, *Wl = nullptr, *Wr = nullptr, *WK = nullptr,
              *WQ = nullptr, *bl = nullptr, *bQ = nullptr;
  int seenDxD = 0, seenAxD = 0;
  for (int i = 0; i < n_in; ++i) {
    int s = in_sizes[i];
    const float* p = (const float*)d_in[i];
    if (s == BB * HH * DD) hist = p;
    else if (s == BB * NN * DD) { /* candidate — unused */ }
    else if (s == DD * DD) { if (seenDxD++ == 0) Wl = p; else Wr = p; }
    else if (s == AA * DD) { if (seenAxD++ == 0) WK = p; else WQ = p; }
    else if (s == DD) bl = p;
    else if (s == AA) bQ = p;
  }

  float* ws = (float*)d_ws;
  float* MTp   = ws + 0;         // 4 * 768*256 = 786432
  float* neigh = ws + 786432;    // 73728
  float* nl    = ws + 860160;    // 73728
  float* u0    = ws + 933888;    // 73728
  float* Qm    = ws + 1007616;   // 24576
  float* vv    = ws + 1032192;   // 73728
  float* wsum  = ws + 1105920;   // 73728  -> total ~4.7 MB
  float* out = (float*)d_out;

  k_prep      <<<dim3(864),    dim3(256), 0, stream>>>(Wr, WK, hist, MTp, neigh);
  k_nl_u0     <<<dim3(24, 32), dim3(256), 0, stream>>>(neigh, hist, Wl, bl, Wr, nl, u0);
  k_q         <<<dim3(8, 32),  dim3(256), 0, stream>>>(u0, WQ, bQ, Qm);
  k_v         <<<dim3(24, 32), dim3(256), 0, stream>>>(Qm, MTp, vv);
  k_attn      <<<dim3(96, 3),  dim3(256), 0, stream>>>(hist, vv, wsum);
  k_orow_write<<<dim3(24, 32), dim3(256), 0, stream>>>(wsum, Wr, nl, out);
}